// Round 14
// baseline (144.913 us; speedup 1.0000x reference)
//
#include <hip/hip_runtime.h>
#include <stdint.h>

#define DIM     300
#define NBATCH  4096
#define NSUP    64      // N*S = 2*32 support cols
#define KP      320     // B K padded to 10*32
#define LSTR    328     // B LDS row stride in ushorts (656 B)
#define SMST    82      // padded sm tile x-stride (floats)
#define SMY     36      // per-channel y extent
#define GRID_G  256     // gemm blocks
#define NTILE   8192    // 16-row tiles total (NBATCH*2)

typedef float f32x4 __attribute__((ext_vector_type(4)));
typedef short s16x8 __attribute__((ext_vector_type(8)));

static __device__ __forceinline__ unsigned bc(float x) { return __builtin_bit_cast(unsigned, x); }
static __device__ __forceinline__ float asf(unsigned u) { return __builtin_bit_cast(float, u); }
static __device__ __forceinline__ unsigned perm_hi(unsigned a, unsigned b) {
    return __builtin_amdgcn_perm(a, b, 0x07060302u);   // [a.hi16 : b.hi16]
}
static __device__ __forceinline__ unsigned short f2bf(float x) {   // RNE (prep only)
    unsigned u = bc(x);
    return (unsigned short)((u + 0x7FFFu + ((u >> 16) & 1u)) >> 16);
}
static __device__ __forceinline__ float bf2f(unsigned short h) { return asf((unsigned)h << 16); }

struct AB { s16x8 h, l; };
// split f32x8 -> bf16 hi (round-half-up) + bf16 lo (residual); accumulates sum of squares
static __device__ __forceinline__ AB cvt_split(float4 c0, float4 c1, float& nrm) {
    nrm = fmaf(c0.x, c0.x, nrm); nrm = fmaf(c0.y, c0.y, nrm);
    nrm = fmaf(c0.z, c0.z, nrm); nrm = fmaf(c0.w, c0.w, nrm);
    nrm = fmaf(c1.x, c1.x, nrm); nrm = fmaf(c1.y, c1.y, nrm);
    nrm = fmaf(c1.z, c1.z, nrm); nrm = fmaf(c1.w, c1.w, nrm);
    const unsigned u0 = bc(c0.x) + 0x8000u, u1 = bc(c0.y) + 0x8000u;
    const unsigned u2 = bc(c0.z) + 0x8000u, u3 = bc(c0.w) + 0x8000u;
    const unsigned u4 = bc(c1.x) + 0x8000u, u5 = bc(c1.y) + 0x8000u;
    const unsigned u6 = bc(c1.z) + 0x8000u, u7 = bc(c1.w) + 0x8000u;
    const float r0 = c0.x - asf(u0 & 0xffff0000u), r1 = c0.y - asf(u1 & 0xffff0000u);
    const float r2 = c0.z - asf(u2 & 0xffff0000u), r3 = c0.w - asf(u3 & 0xffff0000u);
    const float r4 = c1.x - asf(u4 & 0xffff0000u), r5 = c1.y - asf(u5 & 0xffff0000u);
    const float r6 = c1.z - asf(u6 & 0xffff0000u), r7 = c1.w - asf(u7 & 0xffff0000u);
    union { s16x8 v; unsigned u[4]; } H, L;
    H.u[0] = perm_hi(u1, u0); H.u[1] = perm_hi(u3, u2);
    H.u[2] = perm_hi(u5, u4); H.u[3] = perm_hi(u7, u6);
    L.u[0] = perm_hi(bc(r1) + 0x8000u, bc(r0) + 0x8000u);
    L.u[1] = perm_hi(bc(r3) + 0x8000u, bc(r2) + 0x8000u);
    L.u[2] = perm_hi(bc(r5) + 0x8000u, bc(r4) + 0x8000u);
    L.u[3] = perm_hi(bc(r7) + 0x8000u, bc(r6) + 0x8000u);
    AB r; r.h = H.v; r.l = L.v; return r;
}

// ---------------- kernel 1: normalize support vectors -> bf16 hi/lo [64][320]
__global__ __launch_bounds__(64) void prep_kernel(
    const int* __restrict__ sidx, const float* __restrict__ emb,
    unsigned short* __restrict__ Bh, unsigned short* __restrict__ Bl) {
    const int j = blockIdx.x, l = threadIdx.x;
    const size_t tok = (size_t)sidx[j];
    const float* src = emb + tok * DIM;
    float e[5];
    #pragma unroll
    for (int c = 0; c < 5; ++c) {
        const int k = c * 64 + l;
        e[c] = (k < DIM) ? src[k] : 0.f;
    }
    float s = e[0]*e[0] + e[1]*e[1] + e[2]*e[2] + e[3]*e[3] + e[4]*e[4];
    #pragma unroll
    for (int m = 32; m >= 1; m >>= 1) s += __shfl_xor(s, m);
    const float rn = 1.f / fmaxf(sqrtf(s), 1e-8f);
    #pragma unroll
    for (int c = 0; c < 5; ++c) {
        const int k = c * 64 + l;
        const float v = (k < DIM) ? e[c] * rn : 0.f;
        const unsigned short h = f2bf(v);
        Bh[j * KP + k] = h;
        Bl[j * KP + k] = f2bf(v - bf2f(h));
    }
}

// ---------------- kernel 2: barrier-free wave-private gather-GEMM.
// Each wave owns a 16-row x 64-col tile: A direct from emb (in-reg split-bf16,
// converted ONCE), B from LDS (staged once; only barrier in the kernel).
// No __syncthreads in the loop -> no vmcnt(0) drains -> waves self-pipeline.
__global__ __launch_bounds__(512) void gemm_kernel(
    const int* __restrict__ tokens, const float* __restrict__ emb,
    const unsigned short* __restrict__ Bh, const unsigned short* __restrict__ Bl,
    float* __restrict__ smG) {

    __shared__ __attribute__((aligned(16))) unsigned short BhL[NSUP * LSTR]; // 42 KB
    __shared__ __attribute__((aligned(16))) unsigned short BlL[NSUP * LSTR]; // 42 KB

    const int tid = threadIdx.x;
    const int l = tid & 63;
    const int w = tid >> 6;
    const int c = l & 15, hq = l >> 4;

    // ---- stage B [64][320] -> LDS [64][328] (5120 16B chunks, 10/thread)
    #pragma unroll
    for (int m = 0; m < 10; ++m) {
        const int ci = tid + m * 512;            // 0..5119
        const int plane = ci / 2560;
        const int rem = ci - plane * 2560;
        const int rr = rem / 40, jc = rem - rr * 40;
        const uint4 v = *(const uint4*)((plane ? Bl : Bh) + rr * KP + jc * 8);
        *(uint4*)((plane ? BlL : BhL) + rr * LSTR + jc * 8) = v;
    }
    __syncthreads();   // the ONLY barrier

    const int bbl0 = c * LSTR + hq * 8;

    #pragma unroll 1
    for (int i = 0; i < NTILE / (GRID_G * 8); ++i) {
        const int tile = blockIdx.x * 8 + w + i * (GRID_G * 8);
        const size_t tok = (size_t)tokens[tile * 16 + c];
        const float* srcA = emb + tok * DIM;

        f32x4 q0[4] = {{0,0,0,0},{0,0,0,0},{0,0,0,0},{0,0,0,0}};
        f32x4 q1[4] = {{0,0,0,0},{0,0,0,0},{0,0,0,0},{0,0,0,0}};
        f32x4 q2[4] = {{0,0,0,0},{0,0,0,0},{0,0,0,0},{0,0,0,0}};
        float nrm = 0.f;

        #pragma unroll
        for (int t = 0; t < 9; ++t) {
            const float4 c0 = *(const float4*)(srcA + t * 32 + hq * 8);
            const float4 c1 = *(const float4*)(srcA + t * 32 + hq * 8 + 4);
            const AB a = cvt_split(c0, c1, nrm);
            #pragma unroll
            for (int cg = 0; cg < 4; ++cg) {
                const s16x8 bh = *(const s16x8*)(BhL + cg * 16 * LSTR + bbl0 + t * 32);
                const s16x8 bl = *(const s16x8*)(BlL + cg * 16 * LSTR + bbl0 + t * 32);
                q0[cg] = __builtin_amdgcn_mfma_f32_16x16x32_bf16(a.h, bh, q0[cg], 0, 0, 0);
                q1[cg] = __builtin_amdgcn_mfma_f32_16x16x32_bf16(a.h, bl, q1[cg], 0, 0, 0);
                q2[cg] = __builtin_amdgcn_mfma_f32_16x16x32_bf16(a.l, bh, q2[cg], 0, 0, 0);
            }
        }
        {   // t = 9: k = 288 + hq*8 ..; valid k < 300; clamped in-bounds loads + mask
            const float* pc = srcA + ((hq == 0) ? 288 : 292);
            const float4 c0 = *(const float4*)(pc);
            const float4 c1 = *(const float4*)(pc + 4);
            float4 d0, d1;
            d0.x = (hq == 0) ? c0.x : ((hq == 1) ? c1.x : 0.f);
            d0.y = (hq == 0) ? c0.y : ((hq == 1) ? c1.y : 0.f);
            d0.z = (hq == 0) ? c0.z : ((hq == 1) ? c1.z : 0.f);
            d0.w = (hq == 0) ? c0.w : ((hq == 1) ? c1.w : 0.f);
            d1.x = (hq == 0) ? c1.x : 0.f;
            d1.y = (hq == 0) ? c1.y : 0.f;
            d1.z = (hq == 0) ? c1.z : 0.f;
            d1.w = (hq == 0) ? c1.w : 0.f;
            const AB a = cvt_split(d0, d1, nrm);
            #pragma unroll
            for (int cg = 0; cg < 4; ++cg) {
                const s16x8 bh = *(const s16x8*)(BhL + cg * 16 * LSTR + bbl0 + 288);
                const s16x8 bl = *(const s16x8*)(BlL + cg * 16 * LSTR + bbl0 + 288);
                q0[cg] = __builtin_amdgcn_mfma_f32_16x16x32_bf16(a.h, bh, q0[cg], 0, 0, 0);
                q1[cg] = __builtin_amdgcn_mfma_f32_16x16x32_bf16(a.h, bl, q1[cg], 0, 0, 0);
                q2[cg] = __builtin_amdgcn_mfma_f32_16x16x32_bf16(a.l, bh, q2[cg], 0, 0, 0);
            }
        }

        // ---- epilogue: full row norms + scale + coalesced smG stores
        nrm += __shfl_xor(nrm, 16);
        nrm += __shfl_xor(nrm, 32);            // lane (c,*): |row c of tile|^2
        float rn[4];
        #pragma unroll
        for (int q = 0; q < 4; ++q) {
            const float nq = __shfl(nrm, hq * 4 + q);   // norm of row hq*4+q
            rn[q] = __builtin_amdgcn_rcpf(
                fmaxf(__builtin_amdgcn_sqrtf(nq), 1e-8f));
        }
        const int b = tile >> 1, hf = tile & 1;
        #pragma unroll
        for (int cg = 0; cg < 4; ++cg) {
            const int ch = cg >> 1, s = (cg & 1) * 16 + c;
            float4 vv;
            #pragma unroll
            for (int q = 0; q < 4; ++q)
                ((float*)&vv)[q] = (q0[cg][q] + q1[cg][q] + q2[cg][q]) * rn[q];
            // sm[b][ch][s][r], r = hf*16 + hq*4 + q
            *(float4*)(smG + ((size_t)(b * 2 + ch) * 32 + s) * 32 + hf * 16 + hq * 4) = vv;
        }
    }
}

// ---------------- kernel 3: tail per batch (softmax-gate + conv1 + conv2 + fc)
__global__ __launch_bounds__(256) void tail_kernel(
    const float* __restrict__ smG,
    const float* __restrict__ c1w, const float* __restrict__ c1b,
    const float* __restrict__ c2w, const float* __restrict__ c2b,
    const float* __restrict__ f2w, const float* __restrict__ f2b,
    const float* __restrict__ fcw, const float* __restrict__ fcb,
    float* __restrict__ out) {

    __shared__ __attribute__((aligned(16))) float smP[34 * SMST];  // [xp=r+1][ch][yp=s+1]
    __shared__ __attribute__((aligned(16))) float pl1P[2 * 17 * 18];
    __shared__ float scrP[8];    // [0..3]=se_w, [4..7]=sv_w

    const int tid = threadIdx.x;
    const int w = tid >> 6, l = tid & 63;
    const int b = blockIdx.x;

    // P0: zero smP + pl1 borders
    {
        const f32x4 z = {0.f, 0.f, 0.f, 0.f};
        #pragma unroll
        for (int i = 0; i < 3; ++i) {
            const int idx = i * 256 + tid;
            if (idx < 697) ((f32x4*)smP)[idx] = z;
        }
        if (tid >= 190) {
            const int z2 = tid - 190;
            const int ic = (z2 >= 33) ? 1 : 0;
            const int rm = z2 - 33 * ic;
            pl1P[ic * 306 + (rm < 17 ? rm : (rm - 16) * 18)] = 0.f;
        }
    }
    __syncthreads();

    // P1: load sm (coalesced) -> padded LDS + fused softmax partials
    {
        const float* src = smG + (size_t)b * 2048;
        float se = 0.f, sv = 0.f;
        #pragma unroll
        for (int h2 = 0; h2 < 2; ++h2) {
            const int f4 = tid * 2 + h2;            // waves 0-1: ch0; waves 2-3: ch1
            const float4 v = ((const float4*)src)[f4];
            const int base = f4 * 4;
            const int chn = base >> 10;
            const int s = (base >> 5) & 31;
            const int r = base & 31;
            float* dstp = &smP[(r + 1) * SMST + chn * SMY + (s + 1)];
            dstp[0] = v.x; dstp[SMST] = v.y; dstp[2 * SMST] = v.z; dstp[3 * SMST] = v.w;
            const float e0 = __expf(v.x), e1 = __expf(v.y);   // |v|<=1: no max-shift
            const float e2 = __expf(v.z), e3 = __expf(v.w);
            se += e0 + e1 + e2 + e3;
            sv = fmaf(e0, v.x, sv); sv = fmaf(e1, v.y, sv);
            sv = fmaf(e2, v.z, sv); sv = fmaf(e3, v.w, sv);
        }
        #pragma unroll
        for (int m = 32; m >= 1; m >>= 1) { se += __shfl_xor(se, m); sv += __shfl_xor(sv, m); }
        if (l == 0) { scrP[w] = se; scrP[4 + w] = sv; }
    }
    __syncthreads();

    // P2: conv1 (both oc per thread) + gate + relu + maxpool -> pl1P
    {
        const int ii = tid >> 4, jj = tid & 15;
        float pc0[4] = {0,0,0,0}, pc1[4] = {0,0,0,0};
        float pA0[4] = {0,0,0,0}, pA1[4] = {0,0,0,0};
        #pragma unroll
        for (int ic = 0; ic < 2; ++ic) {
            float p[4][4];
            #pragma unroll
            for (int a = 0; a < 4; ++a) {        // xp = 2jj+a, yp base 2ii
                const int off = (2 * jj + a) * SMST + ic * SMY + 2 * ii;
                const float2 v01 = *(const float2*)&smP[off];
                const float2 v23 = *(const float2*)&smP[off + 2];
                p[a][0] = v01.x; p[a][1] = v01.y; p[a][2] = v23.x; p[a][3] = v23.y;
            }
            #pragma unroll
            for (int py = 0; py < 2; ++py)
            #pragma unroll
            for (int px = 0; px < 2; ++px)
            #pragma unroll
            for (int dy = 0; dy < 3; ++dy)
            #pragma unroll
            for (int dx = 0; dx < 3; ++dx) {
                const float pv = p[px + dx][py + dy];
                const int pos = py * 2 + px;
                if (ic == 0) {
                    pc0[pos] = fmaf(c1w[0 * 9 + dy * 3 + dx], pv, pc0[pos]);
                    pc1[pos] = fmaf(c1w[2 * 9 + dy * 3 + dx], pv, pc1[pos]);
                } else {
                    pA0[pos] = fmaf(c1w[1 * 9 + dy * 3 + dx], pv, pA0[pos]);
                    pA1[pos] = fmaf(c1w[3 * 9 + dy * 3 + dx], pv, pA1[pos]);
                }
            }
        }
        const float p0 = (scrP[4] + scrP[5]) / (scrP[0] + scrP[1]);
        const float p1 = (scrP[6] + scrP[7]) / (scrP[2] + scrP[3]);
        const float gg0 = 1.f / (1.f + __expf(-(f2w[0] * p0 + f2w[1] * p1 + f2b[0])));
        const float gg1 = 1.f / (1.f + __expf(-(f2w[2] * p0 + f2w[3] * p1 + f2b[1])));
        const float b0 = c1b[0], b1 = c1b[1];
        float mx0 = 0.f, mx1 = 0.f;   // relu folded
        #pragma unroll
        for (int i = 0; i < 4; ++i) {
            mx0 = fmaxf(mx0, b0 + gg0 * pc0[i] + gg1 * pA0[i]);
            mx1 = fmaxf(mx1, b1 + gg0 * pc1[i] + gg1 * pA1[i]);
        }
        pl1P[0 * 306 + (ii + 1) * 18 + (jj + 1)] = mx0;
        pl1P[1 * 306 + (ii + 1) * 18 + (jj + 1)] = mx1;
    }
    __syncthreads();

    // P3: wave 0: conv2(2x2,pad1)+relu+avgpool2 + fc -> out
    if (w == 0) {
        float o0 = 0.f, o1 = 0.f;
        #pragma unroll
        for (int h = 0; h < 2; ++h) {
            const int o = h * 64 + l, oc2 = o >> 6, ii2 = (o >> 3) & 7, jj2 = o & 7;
            float sum = 0.f;
            #pragma unroll
            for (int py = 0; py < 2; ++py)
            #pragma unroll
            for (int px = 0; px < 2; ++px) {
                const int y = 2 * ii2 + py, x = 2 * jj2 + px;
                float acc = c2b[oc2];
                #pragma unroll
                for (int ic = 0; ic < 2; ++ic)
                #pragma unroll
                for (int dy = 0; dy < 2; ++dy)
                #pragma unroll
                for (int dx = 0; dx < 2; ++dx)
                    acc += c2w[((oc2 * 2 + ic) * 2 + dy) * 2 + dx] *
                           pl1P[ic * 306 + (y + dy) * 18 + (x + dx)];
                sum += fmaxf(acc, 0.f);
            }
            const float val = 0.25f * sum;
            o0 = fmaf(val, fcw[o], o0);
            o1 = fmaf(val, fcw[128 + o], o1);
        }
        #pragma unroll
        for (int m = 32; m >= 1; m >>= 1) { o0 += __shfl_xor(o0, m); o1 += __shfl_xor(o1, m); }
        if (l == 0) {
            out[b * 2 + 0] = fcb[0] + o0;
            out[b * 2 + 1] = fcb[1] + o1;
        }
    }
}

extern "C" void kernel_launch(void* const* d_in, const int* in_sizes, int n_in,
                              void* d_out, int out_size, void* d_ws, size_t ws_size,
                              hipStream_t stream) {
    const int* tokens = (const int*)d_in[0];
    const int* sidx   = (const int*)d_in[1];
    const float* emb  = (const float*)d_in[2];
    const float* c1w  = (const float*)d_in[3];
    const float* c1b  = (const float*)d_in[4];
    const float* c2w  = (const float*)d_in[5];
    const float* c2b  = (const float*)d_in[6];
    const float* f2w  = (const float*)d_in[7];
    const float* f2b  = (const float*)d_in[8];
    const float* fcw  = (const float*)d_in[9];
    const float* fcb  = (const float*)d_in[10];

    // ws layout: [sm f32 4096*2*32*32 = 32 MiB][Bh 40 KiB][Bl 40 KiB]
    float* smG = (float*)d_ws;
    unsigned short* Bh = (unsigned short*)((char*)d_ws + (size_t)NBATCH * 2048 * 4);
    unsigned short* Bl = Bh + NSUP * KP;

    prep_kernel<<<NSUP, 64, 0, stream>>>(sidx, emb, Bh, Bl);
    gemm_kernel<<<GRID_G, 512, 0, stream>>>(tokens, emb, Bh, Bl, smG);
    tail_kernel<<<NBATCH, 256, 0, stream>>>(smG, c1w, c1b, c2w, c2b,
                                            f2w, f2b, fcw, fcb, (float*)d_out);
}

// Round 15
// 74.121 us; speedup vs baseline: 1.9551x; 1.9551x over previous
//
#include <hip/hip_runtime.h>
#include <stdint.h>

#define DIM     300
#define NBATCH  4096
#define NSUP    64      // N*S = 2*32 support cols
#define KP      320     // B K padded to 10*32
#define LSTR    328     // LDS row stride in ushorts for A and B tiles (656 B)
#define SMST    82      // padded sm tile x-stride (floats)
#define SMY     36      // per-channel y extent
#define GRID_G  256     // gemm blocks: 1 per CU (126 KB LDS)
#define PPB     16      // batch panels per gemm block (even: loop unrolled x2)

typedef float f32x4 __attribute__((ext_vector_type(4)));
typedef short s16x8 __attribute__((ext_vector_type(8)));

static __device__ __forceinline__ unsigned bc(float x) { return __builtin_bit_cast(unsigned, x); }
static __device__ __forceinline__ float asf(unsigned u) { return __builtin_bit_cast(float, u); }
static __device__ __forceinline__ unsigned perm_hi(unsigned a, unsigned b) {
    return __builtin_amdgcn_perm(a, b, 0x07060302u);   // [a.hi16 : b.hi16]
}
static __device__ __forceinline__ unsigned short f2bf(float x) {   // RNE (prep only)
    unsigned u = bc(x);
    return (unsigned short)((u + 0x7FFFu + ((u >> 16) & 1u)) >> 16);
}
static __device__ __forceinline__ float bf2f(unsigned short h) { return asf((unsigned)h << 16); }

// ---------------- kernel 1: normalize support vectors -> bf16 hi/lo [64][320]
__global__ __launch_bounds__(64) void prep_kernel(
    const int* __restrict__ sidx, const float* __restrict__ emb,
    unsigned short* __restrict__ Bh, unsigned short* __restrict__ Bl) {
    const int j = blockIdx.x, l = threadIdx.x;
    const size_t tok = (size_t)sidx[j];
    const float* src = emb + tok * DIM;
    float e[5];
    #pragma unroll
    for (int c = 0; c < 5; ++c) {
        const int k = c * 64 + l;
        e[c] = (k < DIM) ? src[k] : 0.f;
    }
    float s = e[0]*e[0] + e[1]*e[1] + e[2]*e[2] + e[3]*e[3] + e[4]*e[4];
    #pragma unroll
    for (int m = 32; m >= 1; m >>= 1) s += __shfl_xor(s, m);
    const float rn = 1.f / fmaxf(sqrtf(s), 1e-8f);
    #pragma unroll
    for (int c = 0; c < 5; ++c) {
        const int k = c * 64 + l;
        const float v = (k < DIM) ? e[c] * rn : 0.f;
        const unsigned short h = f2bf(v);
        Bh[j * KP + k] = h;
        Bl[j * KP + k] = f2bf(v - bf2f(h));
    }
}

// ---------------- kernel 2: persistent gather-GEMM, B resident in LDS,
// DEPTH-2 gather pipeline: two register staging sets; gather for panel p+3
// is issued at end of panel p (two panel-durations to land). Inner MFMA loop
// touches ONLY LDS (no vmcnt) so in-flight gathers never stall it.
__global__ __launch_bounds__(512, 2) void gemm_kernel(
    const int* __restrict__ tokens, const float* __restrict__ emb,
    const unsigned short* __restrict__ Bh, const unsigned short* __restrict__ Bl,
    float* __restrict__ smG) {

    __shared__ __attribute__((aligned(16))) unsigned short BhL[NSUP * LSTR]; // 42 KB
    __shared__ __attribute__((aligned(16))) unsigned short BlL[NSUP * LSTR]; // 42 KB
    __shared__ __attribute__((aligned(16))) unsigned short AhL[32 * LSTR];   // 21 KB
    __shared__ __attribute__((aligned(16))) unsigned short AlL[32 * LSTR];   // 21 KB
    __shared__ __attribute__((aligned(16))) float norms[32];

    const int tid = threadIdx.x;
    const int l = tid & 63;
    const int w = tid >> 6;
    const int c = l & 15, hq = l >> 4;
    const int rb = (w >> 2) * 16;
    const int cg = w & 3;
    const int chn = cg >> 1, sb = (cg & 1) * 16;
    const int bbase = blockIdx.x * PPB;

    // ---- one-time: stage B [64][320] -> LDS [64][328] (5120 16B chunks, 10/thread)
    #pragma unroll
    for (int m = 0; m < 10; ++m) {
        const int ci = tid + m * 512;            // 0..5119
        const int plane = ci / 2560;
        const int rem = ci - plane * 2560;
        const int rr = rem / 40, jc = rem - rr * 40;
        const uint4 v = *(const uint4*)((plane ? Bl : Bh) + rr * KP + jc * 8);
        *(uint4*)((plane ? BlL : BhL) + rr * LSTR + jc * 8) = v;
    }
    // ---- one-time: zero A K-pad (k=300..327), never rewritten by staging
    if (tid < 448) {
        const int row = tid / 14, q = tid - 14 * row;   // 14 uints = 28 ushorts
        ((unsigned*)AhL)[row * 164 + 150 + q] = 0u;
        ((unsigned*)AlL)[row * 164 + 150 + q] = 0u;
    }

    // static staging chunk map: chunk ci = tid + 512*m over [32 rows][75 float4s]
    const int ci1 = tid + 512, ci2 = tid + 1024, ci3 = tid + 1536, ci4 = tid + 2048;
    const int r0 = tid / 75, j0 = tid - 75 * r0;
    const int r1 = ci1 / 75, j1 = ci1 - 75 * r1;
    const int r2 = ci2 / 75, j2 = ci2 - 75 * r2;
    const int r3 = ci3 / 75, j3 = ci3 - 75 * r3;
    const int r4 = ci4 / 75, j4 = ci4 - 75 * r4;
    const bool has4 = (ci4 < 2400);

    const int abase = (rb + c) * LSTR + hq * 8;
    const int bbl   = (cg * 16 + c) * LSTR + hq * 8;

    float4 sA0, sA1, sA2, sA3, sA4;    // staging set A
    float4 sB0, sB1, sB2, sB3, sB4;    // staging set B

    #define ISSUE_GATHER(S0, S1, S2, S3, S4, TB)                                    \
    {                                                                               \
        S0 = *(const float4*)(emb + (size_t)tokens[(TB) + r0] * DIM + j0 * 4);      \
        S1 = *(const float4*)(emb + (size_t)tokens[(TB) + r1] * DIM + j1 * 4);      \
        S2 = *(const float4*)(emb + (size_t)tokens[(TB) + r2] * DIM + j2 * 4);      \
        S3 = *(const float4*)(emb + (size_t)tokens[(TB) + r3] * DIM + j3 * 4);      \
        if (has4) S4 = *(const float4*)(emb + (size_t)tokens[(TB) + r4] * DIM + j4 * 4); \
    }

    #define STORE_CHUNK(ST, R, J)                                                   \
    {                                                                               \
        const unsigned u0 = bc(ST.x) + 0x8000u, u1 = bc(ST.y) + 0x8000u;            \
        const unsigned u2 = bc(ST.z) + 0x8000u, u3 = bc(ST.w) + 0x8000u;            \
        const float q0f = ST.x - asf(u0 & 0xffff0000u);                             \
        const float q1f = ST.y - asf(u1 & 0xffff0000u);                             \
        const float q2f = ST.z - asf(u2 & 0xffff0000u);                             \
        const float q3f = ST.w - asf(u3 & 0xffff0000u);                             \
        *(uint2*)(&AhL[(R) * LSTR + (J) * 4]) =                                     \
            uint2{perm_hi(u1, u0), perm_hi(u3, u2)};                                \
        *(uint2*)(&AlL[(R) * LSTR + (J) * 4]) =                                     \
            uint2{perm_hi(bc(q1f) + 0x8000u, bc(q0f) + 0x8000u),                    \
                  perm_hi(bc(q3f) + 0x8000u, bc(q2f) + 0x8000u)};                   \
    }

    #define STAGE_ALL(S0, S1, S2, S3, S4)                                           \
    {                                                                               \
        STORE_CHUNK(S0, r0, j0); STORE_CHUNK(S1, r1, j1);                           \
        STORE_CHUNK(S2, r2, j2); STORE_CHUNK(S3, r3, j3);                           \
        if (has4) STORE_CHUNK(S4, r4, j4);                                          \
    }

    // one panel's compute: pure-LDS MFMA + Gram norms + epilogue + smG store
    #define COMPUTE_PANEL(PIDX)                                                     \
    {                                                                               \
        f32x4 q0 = {0,0,0,0}, q1 = {0,0,0,0}, q2 = {0,0,0,0};                       \
        f32x4 gv = {0,0,0,0}, g2 = {0,0,0,0};                                       \
        _Pragma("unroll")                                                           \
        for (int t = 0; t < 10; ++t) {                                              \
            const s16x8 ah = *(const s16x8*)(AhL + abase + t * 32);                 \
            const s16x8 al = *(const s16x8*)(AlL + abase + t * 32);                 \
            const s16x8 bh = *(const s16x8*)(BhL + bbl + t * 32);                   \
            const s16x8 bl = *(const s16x8*)(BlL + bbl + t * 32);                   \
            q0 = __builtin_amdgcn_mfma_f32_16x16x32_bf16(ah, bh, q0, 0, 0, 0);      \
            q1 = __builtin_amdgcn_mfma_f32_16x16x32_bf16(ah, bl, q1, 0, 0, 0);      \
            q2 = __builtin_amdgcn_mfma_f32_16x16x32_bf16(al, bh, q2, 0, 0, 0);      \
            gv = __builtin_amdgcn_mfma_f32_16x16x32_bf16(ah, ah, gv, 0, 0, 0);      \
            g2 = __builtin_amdgcn_mfma_f32_16x16x32_bf16(ah, al, g2, 0, 0, 0);      \
        }                                                                           \
        if (hq == (c >> 2)) {                                                       \
            const int q = c & 3;                                                    \
            const float d1 = (q == 0) ? gv[0] : (q == 1) ? gv[1]                    \
                           : (q == 2) ? gv[2] : gv[3];                              \
            const float d2 = (q == 0) ? g2[0] : (q == 1) ? g2[1]                    \
                           : (q == 2) ? g2[2] : g2[3];                              \
            norms[rb + c] = d1 + 2.f * d2;                                          \
        }                                                                           \
        asm volatile("s_waitcnt lgkmcnt(0)" ::: "memory");                          \
        const f32x4 n4 = *(const f32x4*)&norms[rb + hq * 4];                        \
        float4 vv;                                                                  \
        _Pragma("unroll")                                                           \
        for (int q = 0; q < 4; ++q) {                                               \
            const float rn = __builtin_amdgcn_rcpf(                                 \
                fmaxf(__builtin_amdgcn_sqrtf(n4[q]), 1e-8f));                       \
            ((float*)&vv)[q] = (q0[q] + q1[q] + q2[q]) * rn;                        \
        }                                                                           \
        *(float4*)(smG + ((size_t)((PIDX) * 2 + chn) * 32 + sb + c) * 32            \
                   + rb + hq * 4) = vv;                                             \
    }

    // prologue: panel 0 staged; stA <- panel 1; stB <- panel 2 (both in flight)
    ISSUE_GATHER(sA0, sA1, sA2, sA3, sA4, bbase * 32);
    STAGE_ALL(sA0, sA1, sA2, sA3, sA4);
    ISSUE_GATHER(sA0, sA1, sA2, sA3, sA4, (bbase + 1) * 32);
    ISSUE_GATHER(sB0, sB1, sB2, sB3, sB4, (bbase + 2) * 32);
    __builtin_amdgcn_sched_barrier(0);
    __syncthreads();   // panel 0 + B + pads ready

    #pragma unroll 1
    for (int p = 0; p < PPB; p += 2) {
        // ---- body A: compute panel p; stage p+1 from stA; stA <- p+3
        COMPUTE_PANEL(bbase + p);
        __syncthreads();                       // all waves done reading A tile
        STAGE_ALL(sA0, sA1, sA2, sA3, sA4);    // panel p+1 (p+1 <= 15 always here)
        if (p + 3 < PPB)
            ISSUE_GATHER(sA0, sA1, sA2, sA3, sA4, (bbase + p + 3) * 32);
        __builtin_amdgcn_sched_barrier(0);
        __syncthreads();                       // panel p+1 ready

        // ---- body B: compute panel p+1; stage p+2 from stB; stB <- p+4
        COMPUTE_PANEL(bbase + p + 1);
        __syncthreads();                       // all waves done reading A tile
        if (p + 2 < PPB) {
            STAGE_ALL(sB0, sB1, sB2, sB3, sB4);    // panel p+2
            if (p + 4 < PPB)
                ISSUE_GATHER(sB0, sB1, sB2, sB3, sB4, (bbase + p + 4) * 32);
        }
        __builtin_amdgcn_sched_barrier(0);
        __syncthreads();                       // panel p+2 ready
    }
    #undef COMPUTE_PANEL
    #undef STAGE_ALL
    #undef STORE_CHUNK
    #undef ISSUE_GATHER
}

// ---------------- kernel 3: tail per batch (softmax-gate + conv1 + conv2 + fc)
__global__ __launch_bounds__(256) void tail_kernel(
    const float* __restrict__ smG,
    const float* __restrict__ c1w, const float* __restrict__ c1b,
    const float* __restrict__ c2w, const float* __restrict__ c2b,
    const float* __restrict__ f2w, const float* __restrict__ f2b,
    const float* __restrict__ fcw, const float* __restrict__ fcb,
    float* __restrict__ out) {

    __shared__ __attribute__((aligned(16))) float smP[34 * SMST];  // [xp=r+1][ch][yp=s+1]
    __shared__ __attribute__((aligned(16))) float pl1P[2 * 17 * 18];
    __shared__ float scrP[8];    // [0..3]=se_w, [4..7]=sv_w

    const int tid = threadIdx.x;
    const int w = tid >> 6, l = tid & 63;
    const int b = blockIdx.x;

    // P0: zero smP + pl1 borders
    {
        const f32x4 z = {0.f, 0.f, 0.f, 0.f};
        #pragma unroll
        for (int i = 0; i < 3; ++i) {
            const int idx = i * 256 + tid;
            if (idx < 697) ((f32x4*)smP)[idx] = z;
        }
        if (tid >= 190) {
            const int z2 = tid - 190;
            const int ic = (z2 >= 33) ? 1 : 0;
            const int rm = z2 - 33 * ic;
            pl1P[ic * 306 + (rm < 17 ? rm : (rm - 16) * 18)] = 0.f;
        }
    }
    __syncthreads();

    // P1: load sm (coalesced) -> padded LDS + fused softmax partials
    {
        const float* src = smG + (size_t)b * 2048;
        float se = 0.f, sv = 0.f;
        #pragma unroll
        for (int h2 = 0; h2 < 2; ++h2) {
            const int f4 = tid * 2 + h2;            // waves 0-1: ch0; waves 2-3: ch1
            const float4 v = ((const float4*)src)[f4];
            const int base = f4 * 4;
            const int chn = base >> 10;
            const int s = (base >> 5) & 31;
            const int r = base & 31;
            float* dstp = &smP[(r + 1) * SMST + chn * SMY + (s + 1)];
            dstp[0] = v.x; dstp[SMST] = v.y; dstp[2 * SMST] = v.z; dstp[3 * SMST] = v.w;
            const float e0 = __expf(v.x), e1 = __expf(v.y);   // |v|<=1: no max-shift
            const float e2 = __expf(v.z), e3 = __expf(v.w);
            se += e0 + e1 + e2 + e3;
            sv = fmaf(e0, v.x, sv); sv = fmaf(e1, v.y, sv);
            sv = fmaf(e2, v.z, sv); sv = fmaf(e3, v.w, sv);
        }
        #pragma unroll
        for (int m = 32; m >= 1; m >>= 1) { se += __shfl_xor(se, m); sv += __shfl_xor(sv, m); }
        if (l == 0) { scrP[w] = se; scrP[4 + w] = sv; }
    }
    __syncthreads();

    // P2: conv1 (both oc per thread) + gate + relu + maxpool -> pl1P
    {
        const int ii = tid >> 4, jj = tid & 15;
        float pc0[4] = {0,0,0,0}, pc1[4] = {0,0,0,0};
        float pA0[4] = {0,0,0,0}, pA1[4] = {0,0,0,0};
        #pragma unroll
        for (int ic = 0; ic < 2; ++ic) {
            float p[4][4];
            #pragma unroll
            for (int a = 0; a < 4; ++a) {        // xp = 2jj+a, yp base 2ii
                const int off = (2 * jj + a) * SMST + ic * SMY + 2 * ii;
                const float2 v01 = *(const float2*)&smP[off];
                const float2 v23 = *(const float2*)&smP[off + 2];
                p[a][0] = v01.x; p[a][1] = v01.y; p[a][2] = v23.x; p[a][3] = v23.y;
            }
            #pragma unroll
            for (int py = 0; py < 2; ++py)
            #pragma unroll
            for (int px = 0; px < 2; ++px)
            #pragma unroll
            for (int dy = 0; dy < 3; ++dy)
            #pragma unroll
            for (int dx = 0; dx < 3; ++dx) {
                const float pv = p[px + dx][py + dy];
                const int pos = py * 2 + px;
                if (ic == 0) {
                    pc0[pos] = fmaf(c1w[0 * 9 + dy * 3 + dx], pv, pc0[pos]);
                    pc1[pos] = fmaf(c1w[2 * 9 + dy * 3 + dx], pv, pc1[pos]);
                } else {
                    pA0[pos] = fmaf(c1w[1 * 9 + dy * 3 + dx], pv, pA0[pos]);
                    pA1[pos] = fmaf(c1w[3 * 9 + dy * 3 + dx], pv, pA1[pos]);
                }
            }
        }
        const float p0 = (scrP[4] + scrP[5]) / (scrP[0] + scrP[1]);
        const float p1 = (scrP[6] + scrP[7]) / (scrP[2] + scrP[3]);
        const float gg0 = 1.f / (1.f + __expf(-(f2w[0] * p0 + f2w[1] * p1 + f2b[0])));
        const float gg1 = 1.f / (1.f + __expf(-(f2w[2] * p0 + f2w[3] * p1 + f2b[1])));
        const float b0 = c1b[0], b1 = c1b[1];
        float mx0 = 0.f, mx1 = 0.f;   // relu folded
        #pragma unroll
        for (int i = 0; i < 4; ++i) {
            mx0 = fmaxf(mx0, b0 + gg0 * pc0[i] + gg1 * pA0[i]);
            mx1 = fmaxf(mx1, b1 + gg0 * pc1[i] + gg1 * pA1[i]);
        }
        pl1P[0 * 306 + (ii + 1) * 18 + (jj + 1)] = mx0;
        pl1P[1 * 306 + (ii + 1) * 18 + (jj + 1)] = mx1;
    }
    __syncthreads();

    // P3: wave 0: conv2(2x2,pad1)+relu+avgpool2 + fc -> out
    if (w == 0) {
        float o0 = 0.f, o1 = 0.f;
        #pragma unroll
        for (int h = 0; h < 2; ++h) {
            const int o = h * 64 + l, oc2 = o >> 6, ii2 = (o >> 3) & 7, jj2 = o & 7;
            float sum = 0.f;
            #pragma unroll
            for (int py = 0; py < 2; ++py)
            #pragma unroll
            for (int px = 0; px < 2; ++px) {
                const int y = 2 * ii2 + py, x = 2 * jj2 + px;
                float acc = c2b[oc2];
                #pragma unroll
                for (int ic = 0; ic < 2; ++ic)
                #pragma unroll
                for (int dy = 0; dy < 2; ++dy)
                #pragma unroll
                for (int dx = 0; dx < 2; ++dx)
                    acc += c2w[((oc2 * 2 + ic) * 2 + dy) * 2 + dx] *
                           pl1P[ic * 306 + (y + dy) * 18 + (x + dx)];
                sum += fmaxf(acc, 0.f);
            }
            const float val = 0.25f * sum;
            o0 = fmaf(val, fcw[o], o0);
            o1 = fmaf(val, fcw[128 + o], o1);
        }
        #pragma unroll
        for (int m = 32; m >= 1; m >>= 1) { o0 += __shfl_xor(o0, m); o1 += __shfl_xor(o1, m); }
        if (l == 0) {
            out[b * 2 + 0] = fcb[0] + o0;
            out[b * 2 + 1] = fcb[1] + o1;
        }
    }
}

extern "C" void kernel_launch(void* const* d_in, const int* in_sizes, int n_in,
                              void* d_out, int out_size, void* d_ws, size_t ws_size,
                              hipStream_t stream) {
    const int* tokens = (const int*)d_in[0];
    const int* sidx   = (const int*)d_in[1];
    const float* emb  = (const float*)d_in[2];
    const float* c1w  = (const float*)d_in[3];
    const float* c1b  = (const float*)d_in[4];
    const float* c2w  = (const float*)d_in[5];
    const float* c2b  = (const float*)d_in[6];
    const float* f2w  = (const float*)d_in[7];
    const float* f2b  = (const float*)d_in[8];
    const float* fcw  = (const float*)d_in[9];
    const float* fcb  = (const float*)d_in[10];

    // ws layout: [sm f32 4096*2*32*32 = 32 MiB][Bh 40 KiB][Bl 40 KiB]
    float* smG = (float*)d_ws;
    unsigned short* Bh = (unsigned short*)((char*)d_ws + (size_t)NBATCH * 2048 * 4);
    unsigned short* Bl = Bh + NSUP * KP;

    prep_kernel<<<NSUP, 64, 0, stream>>>(sidx, emb, Bh, Bl);
    gemm_kernel<<<GRID_G, 512, 0, stream>>>(tokens, emb, Bh, Bl, smG);
    tail_kernel<<<NBATCH, 256, 0, stream>>>(smG, c1w, c1b, c2w, c2b,
                                            f2w, f2b, fcw, fcb, (float*)d_out);
}

// Round 16
// 68.805 us; speedup vs baseline: 2.1061x; 1.0773x over previous
//
#include <hip/hip_runtime.h>
#include <stdint.h>

#define DIM     300
#define NBATCH  4096
#define NSUP    64      // N*S = 2*32 support cols
#define KP      320     // B K padded to 10*32
#define LSTR    328     // LDS row stride in ushorts for A and B tiles (656 B)
#define SMST    82      // padded sm tile x-stride (floats)
#define SMY     36      // per-channel y extent
#define GRID_G  256     // gemm blocks: 1 per CU (126 KB LDS)
#define PPB     16      // batch panels per gemm block

typedef float f32x4 __attribute__((ext_vector_type(4)));
typedef short s16x8 __attribute__((ext_vector_type(8)));

static __device__ __forceinline__ unsigned bc(float x) { return __builtin_bit_cast(unsigned, x); }
static __device__ __forceinline__ float asf(unsigned u) { return __builtin_bit_cast(float, u); }
static __device__ __forceinline__ unsigned perm_hi(unsigned a, unsigned b) {
    return __builtin_amdgcn_perm(a, b, 0x07060302u);   // [a.hi16 : b.hi16]
}
static __device__ __forceinline__ unsigned short f2bf(float x) {   // RNE (prep only)
    unsigned u = bc(x);
    return (unsigned short)((u + 0x7FFFu + ((u >> 16) & 1u)) >> 16);
}
static __device__ __forceinline__ float bf2f(unsigned short h) { return asf((unsigned)h << 16); }

// ---------------- kernel 1: normalize support vectors -> bf16 hi/lo [64][320]
__global__ __launch_bounds__(64) void prep_kernel(
    const int* __restrict__ sidx, const float* __restrict__ emb,
    unsigned short* __restrict__ Bh, unsigned short* __restrict__ Bl) {
    const int j = blockIdx.x, l = threadIdx.x;
    const size_t tok = (size_t)sidx[j];
    const float* src = emb + tok * DIM;
    float e[5];
    #pragma unroll
    for (int c = 0; c < 5; ++c) {
        const int k = c * 64 + l;
        e[c] = (k < DIM) ? src[k] : 0.f;
    }
    float s = e[0]*e[0] + e[1]*e[1] + e[2]*e[2] + e[3]*e[3] + e[4]*e[4];
    #pragma unroll
    for (int m = 32; m >= 1; m >>= 1) s += __shfl_xor(s, m);
    const float rn = 1.f / fmaxf(sqrtf(s), 1e-8f);
    #pragma unroll
    for (int c = 0; c < 5; ++c) {
        const int k = c * 64 + l;
        const float v = (k < DIM) ? e[c] * rn : 0.f;
        const unsigned short h = f2bf(v);
        Bh[j * KP + k] = h;
        Bl[j * KP + k] = f2bf(v - bf2f(h));
    }
}

// ---------------- kernel 2: persistent gather-GEMM, B resident in LDS.
// Inner MFMA loop touches ONLY LDS. Panel barriers are RAW s_barrier with
// lgkmcnt(0) only -- vmcnt is NEVER force-drained, so in-flight HBM gathers
// (issued before the loop) ride across barriers and are consumed by STAGE
// with compiler-counted vmcnt (T4).
__global__ __launch_bounds__(512) void gemm_kernel(
    const int* __restrict__ tokens, const float* __restrict__ emb,
    const unsigned short* __restrict__ Bh, const unsigned short* __restrict__ Bl,
    float* __restrict__ smG) {

    __shared__ __attribute__((aligned(16))) unsigned short BhL[NSUP * LSTR]; // 42 KB
    __shared__ __attribute__((aligned(16))) unsigned short BlL[NSUP * LSTR]; // 42 KB
    __shared__ __attribute__((aligned(16))) unsigned short AhL[32 * LSTR];   // 21 KB
    __shared__ __attribute__((aligned(16))) unsigned short AlL[32 * LSTR];   // 21 KB
    __shared__ __attribute__((aligned(16))) float norms[32];

    const int tid = threadIdx.x;
    const int l = tid & 63;
    const int w = tid >> 6;
    const int c = l & 15, hq = l >> 4;
    const int rb = (w >> 2) * 16;
    const int cg = w & 3;
    const int chn = cg >> 1, sb = (cg & 1) * 16;
    const int bbase = blockIdx.x * PPB;

    // ---- one-time: stage B [64][320] -> LDS [64][328] (5120 16B chunks, 10/thread)
    #pragma unroll
    for (int m = 0; m < 10; ++m) {
        const int ci = tid + m * 512;            // 0..5119
        const int plane = ci / 2560;
        const int rem = ci - plane * 2560;
        const int rr = rem / 40, jc = rem - rr * 40;
        const uint4 v = *(const uint4*)((plane ? Bl : Bh) + rr * KP + jc * 8);
        *(uint4*)((plane ? BlL : BhL) + rr * LSTR + jc * 8) = v;
    }
    // ---- one-time: zero A K-pad (k=300..327), never rewritten by staging
    if (tid < 448) {
        const int row = tid / 14, q = tid - 14 * row;   // 14 uints = 28 ushorts
        ((unsigned*)AhL)[row * 164 + 150 + q] = 0u;
        ((unsigned*)AlL)[row * 164 + 150 + q] = 0u;
    }

    // static staging chunk map: chunk ci = tid + 512*m over [32 rows][75 float4s]
    const int ci1 = tid + 512, ci2 = tid + 1024, ci3 = tid + 1536, ci4 = tid + 2048;
    const int r0 = tid / 75, j0 = tid - 75 * r0;
    const int r1 = ci1 / 75, j1 = ci1 - 75 * r1;
    const int r2 = ci2 / 75, j2 = ci2 - 75 * r2;
    const int r3 = ci3 / 75, j3 = ci3 - 75 * r3;
    const int r4 = ci4 / 75, j4 = ci4 - 75 * r4;
    const bool has4 = (ci4 < 2400);

    const int abase = (rb + c) * LSTR + hq * 8;
    const int bbl   = (cg * 16 + c) * LSTR + hq * 8;

    float4 st0, st1, st2, st3, st4;

    #define ISSUE_GATHER(TB)                                                        \
    {                                                                               \
        st0 = *(const float4*)(emb + (size_t)tokens[(TB) + r0] * DIM + j0 * 4);     \
        st1 = *(const float4*)(emb + (size_t)tokens[(TB) + r1] * DIM + j1 * 4);     \
        st2 = *(const float4*)(emb + (size_t)tokens[(TB) + r2] * DIM + j2 * 4);     \
        st3 = *(const float4*)(emb + (size_t)tokens[(TB) + r3] * DIM + j3 * 4);     \
        if (has4) st4 = *(const float4*)(emb + (size_t)tokens[(TB) + r4] * DIM + j4 * 4); \
    }

    #define STORE_CHUNK(ST, R, J)                                                   \
    {                                                                               \
        const unsigned u0 = bc(ST.x) + 0x8000u, u1 = bc(ST.y) + 0x8000u;            \
        const unsigned u2 = bc(ST.z) + 0x8000u, u3 = bc(ST.w) + 0x8000u;            \
        const float q0f = ST.x - asf(u0 & 0xffff0000u);                             \
        const float q1f = ST.y - asf(u1 & 0xffff0000u);                             \
        const float q2f = ST.z - asf(u2 & 0xffff0000u);                             \
        const float q3f = ST.w - asf(u3 & 0xffff0000u);                             \
        *(uint2*)(&AhL[(R) * LSTR + (J) * 4]) =                                     \
            uint2{perm_hi(u1, u0), perm_hi(u3, u2)};                                \
        *(uint2*)(&AlL[(R) * LSTR + (J) * 4]) =                                     \
            uint2{perm_hi(bc(q1f) + 0x8000u, bc(q0f) + 0x8000u),                    \
                  perm_hi(bc(q3f) + 0x8000u, bc(q2f) + 0x8000u)};                   \
    }

    #define STAGE_ALL()                                                             \
    {                                                                               \
        STORE_CHUNK(st0, r0, j0); STORE_CHUNK(st1, r1, j1);                         \
        STORE_CHUNK(st2, r2, j2); STORE_CHUNK(st3, r3, j3);                         \
        if (has4) STORE_CHUNK(st4, r4, j4);                                         \
    }

    // raw barrier: wait own LDS ops only (lgkm), do NOT drain vmcnt
    #define RAW_BARRIER()                                                           \
    {                                                                               \
        asm volatile("s_waitcnt lgkmcnt(0)" ::: "memory");                          \
        __builtin_amdgcn_s_barrier();                                               \
        __builtin_amdgcn_sched_barrier(0);                                          \
    }

    // prologue: gather + stage panel 0 (full drain once is fine here)
    ISSUE_GATHER(bbase * 32);
    STAGE_ALL();
    __syncthreads();   // one full-drain barrier at start only

    #pragma unroll 1
    for (int p = 0; p < PPB; ++p) {
        // issue next panel's gathers NOW: they ride vmcnt; the loop below and the
        // raw barriers never drain vmcnt, so they overlap compute fully.
        if (p + 1 < PPB) ISSUE_GATHER((bbase + p + 1) * 32);
        __builtin_amdgcn_sched_barrier(0);

        // pure-LDS MFMA loop + Gram norms
        f32x4 q0 = {0,0,0,0}, q1 = {0,0,0,0}, q2 = {0,0,0,0};
        f32x4 gv = {0,0,0,0}, g2 = {0,0,0,0};
        #pragma unroll
        for (int t = 0; t < 10; ++t) {
            const s16x8 ah = *(const s16x8*)(AhL + abase + t * 32);
            const s16x8 al = *(const s16x8*)(AlL + abase + t * 32);
            const s16x8 bh = *(const s16x8*)(BhL + bbl + t * 32);
            const s16x8 bl = *(const s16x8*)(BlL + bbl + t * 32);
            q0 = __builtin_amdgcn_mfma_f32_16x16x32_bf16(ah, bh, q0, 0, 0, 0);
            q1 = __builtin_amdgcn_mfma_f32_16x16x32_bf16(ah, bl, q1, 0, 0, 0);
            q2 = __builtin_amdgcn_mfma_f32_16x16x32_bf16(al, bh, q2, 0, 0, 0);
            gv = __builtin_amdgcn_mfma_f32_16x16x32_bf16(ah, ah, gv, 0, 0, 0);
            g2 = __builtin_amdgcn_mfma_f32_16x16x32_bf16(ah, al, g2, 0, 0, 0);
        }

        // diagonal lanes own |row rb+c|^2 (4 col-group waves race: identical values)
        if (hq == (c >> 2)) {
            const int q = c & 3;
            const float d1 = (q == 0) ? gv[0] : (q == 1) ? gv[1] : (q == 2) ? gv[2] : gv[3];
            const float d2 = (q == 0) ? g2[0] : (q == 1) ? g2[1] : (q == 2) ? g2[2] : g2[3];
            norms[rb + c] = d1 + 2.f * d2;
        }
        asm volatile("s_waitcnt lgkmcnt(0)" ::: "memory");   // intra-wave write->read
        const f32x4 n4 = *(const f32x4*)&norms[rb + hq * 4];
        float4 vv;
        #pragma unroll
        for (int q = 0; q < 4; ++q) {
            const float rn = __builtin_amdgcn_rcpf(
                fmaxf(__builtin_amdgcn_sqrtf(n4[q]), 1e-8f));
            ((float*)&vv)[q] = (q0[q] + q1[q] + q2[q]) * rn;
        }
        // coalesced sm store [b][ch][s][r] (global store rides vmcnt; never drained)
        *(float4*)(smG + ((size_t)((bbase + p) * 2 + chn) * 32 + sb + c) * 32 + rb + hq * 4) = vv;

        RAW_BARRIER();      // all waves done READING A tiles (own lgkm + barrier)
        if (p + 1 < PPB) {
            // gathers had the whole MFMA loop to land; compiler emits counted
            // vmcnt waits for st0..st4 consumption here.
            STAGE_ALL();
        }
        RAW_BARRIER();      // next panel's A tiles visible to all waves
    }
    #undef RAW_BARRIER
    #undef STAGE_ALL
    #undef STORE_CHUNK
    #undef ISSUE_GATHER
}

// ---------------- kernel 3: tail per batch (softmax-gate + conv1 + conv2 + fc)
__global__ __launch_bounds__(256) void tail_kernel(
    const float* __restrict__ smG,
    const float* __restrict__ c1w, const float* __restrict__ c1b,
    const float* __restrict__ c2w, const float* __restrict__ c2b,
    const float* __restrict__ f2w, const float* __restrict__ f2b,
    const float* __restrict__ fcw, const float* __restrict__ fcb,
    float* __restrict__ out) {

    __shared__ __attribute__((aligned(16))) float smP[34 * SMST];  // [xp=r+1][ch][yp=s+1]
    __shared__ __attribute__((aligned(16))) float pl1P[2 * 17 * 18];
    __shared__ float scrP[8];    // [0..3]=se_w, [4..7]=sv_w

    const int tid = threadIdx.x;
    const int w = tid >> 6, l = tid & 63;
    const int b = blockIdx.x;

    // P0: zero smP + pl1 borders
    {
        const f32x4 z = {0.f, 0.f, 0.f, 0.f};
        #pragma unroll
        for (int i = 0; i < 3; ++i) {
            const int idx = i * 256 + tid;
            if (idx < 697) ((f32x4*)smP)[idx] = z;
        }
        if (tid >= 190) {
            const int z2 = tid - 190;
            const int ic = (z2 >= 33) ? 1 : 0;
            const int rm = z2 - 33 * ic;
            pl1P[ic * 306 + (rm < 17 ? rm : (rm - 16) * 18)] = 0.f;
        }
    }
    __syncthreads();

    // P1: load sm (coalesced) -> padded LDS + fused softmax partials
    {
        const float* src = smG + (size_t)b * 2048;
        float se = 0.f, sv = 0.f;
        #pragma unroll
        for (int h2 = 0; h2 < 2; ++h2) {
            const int f4 = tid * 2 + h2;            // waves 0-1: ch0; waves 2-3: ch1
            const float4 v = ((const float4*)src)[f4];
            const int base = f4 * 4;
            const int chn = base >> 10;
            const int s = (base >> 5) & 31;
            const int r = base & 31;
            float* dstp = &smP[(r + 1) * SMST + chn * SMY + (s + 1)];
            dstp[0] = v.x; dstp[SMST] = v.y; dstp[2 * SMST] = v.z; dstp[3 * SMST] = v.w;
            const float e0 = __expf(v.x), e1 = __expf(v.y);   // |v|<=1: no max-shift
            const float e2 = __expf(v.z), e3 = __expf(v.w);
            se += e0 + e1 + e2 + e3;
            sv = fmaf(e0, v.x, sv); sv = fmaf(e1, v.y, sv);
            sv = fmaf(e2, v.z, sv); sv = fmaf(e3, v.w, sv);
        }
        #pragma unroll
        for (int m = 32; m >= 1; m >>= 1) { se += __shfl_xor(se, m); sv += __shfl_xor(sv, m); }
        if (l == 0) { scrP[w] = se; scrP[4 + w] = sv; }
    }
    __syncthreads();

    // P2: conv1 (both oc per thread) + gate + relu + maxpool -> pl1P
    {
        const int ii = tid >> 4, jj = tid & 15;
        float pc0[4] = {0,0,0,0}, pc1[4] = {0,0,0,0};
        float pA0[4] = {0,0,0,0}, pA1[4] = {0,0,0,0};
        #pragma unroll
        for (int ic = 0; ic < 2; ++ic) {
            float p[4][4];
            #pragma unroll
            for (int a = 0; a < 4; ++a) {        // xp = 2jj+a, yp base 2ii
                const int off = (2 * jj + a) * SMST + ic * SMY + 2 * ii;
                const float2 v01 = *(const float2*)&smP[off];
                const float2 v23 = *(const float2*)&smP[off + 2];
                p[a][0] = v01.x; p[a][1] = v01.y; p[a][2] = v23.x; p[a][3] = v23.y;
            }
            #pragma unroll
            for (int py = 0; py < 2; ++py)
            #pragma unroll
            for (int px = 0; px < 2; ++px)
            #pragma unroll
            for (int dy = 0; dy < 3; ++dy)
            #pragma unroll
            for (int dx = 0; dx < 3; ++dx) {
                const float pv = p[px + dx][py + dy];
                const int pos = py * 2 + px;
                if (ic == 0) {
                    pc0[pos] = fmaf(c1w[0 * 9 + dy * 3 + dx], pv, pc0[pos]);
                    pc1[pos] = fmaf(c1w[2 * 9 + dy * 3 + dx], pv, pc1[pos]);
                } else {
                    pA0[pos] = fmaf(c1w[1 * 9 + dy * 3 + dx], pv, pA0[pos]);
                    pA1[pos] = fmaf(c1w[3 * 9 + dy * 3 + dx], pv, pA1[pos]);
                }
            }
        }
        const float p0 = (scrP[4] + scrP[5]) / (scrP[0] + scrP[1]);
        const float p1 = (scrP[6] + scrP[7]) / (scrP[2] + scrP[3]);
        const float gg0 = 1.f / (1.f + __expf(-(f2w[0] * p0 + f2w[1] * p1 + f2b[0])));
        const float gg1 = 1.f / (1.f + __expf(-(f2w[2] * p0 + f2w[3] * p1 + f2b[1])));
        const float b0 = c1b[0], b1 = c1b[1];
        float mx0 = 0.f, mx1 = 0.f;   // relu folded
        #pragma unroll
        for (int i = 0; i < 4; ++i) {
            mx0 = fmaxf(mx0, b0 + gg0 * pc0[i] + gg1 * pA0[i]);
            mx1 = fmaxf(mx1, b1 + gg0 * pc1[i] + gg1 * pA1[i]);
        }
        pl1P[0 * 306 + (ii + 1) * 18 + (jj + 1)] = mx0;
        pl1P[1 * 306 + (ii + 1) * 18 + (jj + 1)] = mx1;
    }
    __syncthreads();

    // P3: wave 0: conv2(2x2,pad1)+relu+avgpool2 + fc -> out
    if (w == 0) {
        float o0 = 0.f, o1 = 0.f;
        #pragma unroll
        for (int h = 0; h < 2; ++h) {
            const int o = h * 64 + l, oc2 = o >> 6, ii2 = (o >> 3) & 7, jj2 = o & 7;
            float sum = 0.f;
            #pragma unroll
            for (int py = 0; py < 2; ++py)
            #pragma unroll
            for (int px = 0; px < 2; ++px) {
                const int y = 2 * ii2 + py, x = 2 * jj2 + px;
                float acc = c2b[oc2];
                #pragma unroll
                for (int ic = 0; ic < 2; ++ic)
                #pragma unroll
                for (int dy = 0; dy < 2; ++dy)
                #pragma unroll
                for (int dx = 0; dx < 2; ++dx)
                    acc += c2w[((oc2 * 2 + ic) * 2 + dy) * 2 + dx] *
                           pl1P[ic * 306 + (y + dy) * 18 + (x + dx)];
                sum += fmaxf(acc, 0.f);
            }
            const float val = 0.25f * sum;
            o0 = fmaf(val, fcw[o], o0);
            o1 = fmaf(val, fcw[128 + o], o1);
        }
        #pragma unroll
        for (int m = 32; m >= 1; m >>= 1) { o0 += __shfl_xor(o0, m); o1 += __shfl_xor(o1, m); }
        if (l == 0) {
            out[b * 2 + 0] = fcb[0] + o0;
            out[b * 2 + 1] = fcb[1] + o1;
        }
    }
}

extern "C" void kernel_launch(void* const* d_in, const int* in_sizes, int n_in,
                              void* d_out, int out_size, void* d_ws, size_t ws_size,
                              hipStream_t stream) {
    const int* tokens = (const int*)d_in[0];
    const int* sidx   = (const int*)d_in[1];
    const float* emb  = (const float*)d_in[2];
    const float* c1w  = (const float*)d_in[3];
    const float* c1b  = (const float*)d_in[4];
    const float* c2w  = (const float*)d_in[5];
    const float* c2b  = (const float*)d_in[6];
    const float* f2w  = (const float*)d_in[7];
    const float* f2b  = (const float*)d_in[8];
    const float* fcw  = (const float*)d_in[9];
    const float* fcb  = (const float*)d_in[10];

    // ws layout: [sm f32 4096*2*32*32 = 32 MiB][Bh 40 KiB][Bl 40 KiB]
    float* smG = (float*)d_ws;
    unsigned short* Bh = (unsigned short*)((char*)d_ws + (size_t)NBATCH * 2048 * 4);
    unsigned short* Bl = Bh + NSUP * KP;

    prep_kernel<<<NSUP, 64, 0, stream>>>(sidx, emb, Bh, Bl);
    gemm_kernel<<<GRID_G, 512, 0, stream>>>(tokens, emb, Bh, Bl, smG);
    tail_kernel<<<NBATCH, 256, 0, stream>>>(smG, c1w, c1b, c2w, c2b,
                                            f2w, f2b, fcw, fcb, (float*)d_out);
}

// Round 17
// 66.413 us; speedup vs baseline: 2.1820x; 1.0360x over previous
//
#include <hip/hip_runtime.h>
#include <stdint.h>

#define DIM     300
#define NBATCH  4096
#define NSUP    64      // N*S = 2*32 support cols
#define KP      320     // B K padded to 10*32
#define LSTR    328     // A LDS row stride in ushorts (656 B, bank-staggered)
#define SMST    82      // padded sm tile x-stride (floats)
#define SMY     36      // per-channel y extent
#define GRID_G  256     // gemm blocks: 1 per CU
#define PPB     16      // batch panels per gemm block

typedef float f32x4 __attribute__((ext_vector_type(4)));
typedef short s16x8 __attribute__((ext_vector_type(8)));

static __device__ __forceinline__ unsigned bc(float x) { return __builtin_bit_cast(unsigned, x); }
static __device__ __forceinline__ float asf(unsigned u) { return __builtin_bit_cast(float, u); }
static __device__ __forceinline__ unsigned perm_hi(unsigned a, unsigned b) {
    return __builtin_amdgcn_perm(a, b, 0x07060302u);   // [a.hi16 : b.hi16]
}
static __device__ __forceinline__ unsigned short f2bf(float x) {   // RNE (prep only)
    unsigned u = bc(x);
    return (unsigned short)((u + 0x7FFFu + ((u >> 16) & 1u)) >> 16);
}
static __device__ __forceinline__ float bf2f(unsigned short h) { return asf((unsigned)h << 16); }

// ---------------- kernel 1: normalize support vectors -> bf16 hi/lo [64][320]
__global__ __launch_bounds__(64) void prep_kernel(
    const int* __restrict__ sidx, const float* __restrict__ emb,
    unsigned short* __restrict__ Bh, unsigned short* __restrict__ Bl) {
    const int j = blockIdx.x, l = threadIdx.x;
    const size_t tok = (size_t)sidx[j];
    const float* src = emb + tok * DIM;
    float e[5];
    #pragma unroll
    for (int c = 0; c < 5; ++c) {
        const int k = c * 64 + l;
        e[c] = (k < DIM) ? src[k] : 0.f;
    }
    float s = e[0]*e[0] + e[1]*e[1] + e[2]*e[2] + e[3]*e[3] + e[4]*e[4];
    #pragma unroll
    for (int m = 32; m >= 1; m >>= 1) s += __shfl_xor(s, m);
    const float rn = 1.f / fmaxf(sqrtf(s), 1e-8f);
    #pragma unroll
    for (int c = 0; c < 5; ++c) {
        const int k = c * 64 + l;
        const float v = (k < DIM) ? e[c] * rn : 0.f;
        const unsigned short h = f2bf(v);
        Bh[j * KP + k] = h;
        Bl[j * KP + k] = f2bf(v - bf2f(h));
    }
}

// ---------------- kernel 2: persistent gather-GEMM (R12 structure).
// A double-buffered in LDS; B streamed from L2 in the MFMA loop; ONE barrier
// per panel, and it is a raw lgkm-only barrier (no forced vmcnt drain) so
// in-flight next-panel gathers are never serialized by the barrier.
__global__ __launch_bounds__(512, 2) void gemm_kernel(
    const int* __restrict__ tokens, const float* __restrict__ emb,
    const unsigned short* __restrict__ Bh, const unsigned short* __restrict__ Bl,
    float* __restrict__ smG) {

    __shared__ __attribute__((aligned(16))) unsigned short AhL[2][32 * LSTR];  // 2x21 KB
    __shared__ __attribute__((aligned(16))) unsigned short AlL[2][32 * LSTR];  // 2x21 KB
    __shared__ __attribute__((aligned(16))) float norms[32];

    const int tid = threadIdx.x;
    const int l = tid & 63;
    const int w = tid >> 6;
    const int c = l & 15, hq = l >> 4;
    const int rb = (w >> 2) * 16;
    const int cg = w & 3;
    const int chn = cg >> 1, sb = (cg & 1) * 16;
    const int bbase = blockIdx.x * PPB;

    // ---- one-time: zero A K-pad (k=300..327) in BOTH buffers
    if (tid < 448) {
        const int row = tid / 14, q = tid - 14 * row;   // 14 uints = 28 ushorts
        ((unsigned*)AhL[0])[row * 164 + 150 + q] = 0u;
        ((unsigned*)AlL[0])[row * 164 + 150 + q] = 0u;
        ((unsigned*)AhL[1])[row * 164 + 150 + q] = 0u;
        ((unsigned*)AlL[1])[row * 164 + 150 + q] = 0u;
    }

    // static staging chunk map: chunk ci = tid + 512*m over [32 rows][75 float4s]
    const int ci1 = tid + 512, ci2 = tid + 1024, ci3 = tid + 1536, ci4 = tid + 2048;
    const int r0 = tid / 75, j0 = tid - 75 * r0;
    const int r1 = ci1 / 75, j1 = ci1 - 75 * r1;
    const int r2 = ci2 / 75, j2 = ci2 - 75 * r2;
    const int r3 = ci3 / 75, j3 = ci3 - 75 * r3;
    const int r4 = ci4 / 75, j4 = ci4 - 75 * r4;
    const bool has4 = (ci4 < 2400);

    const int abase = (rb + c) * LSTR + hq * 8;
    const unsigned short* pBh = Bh + (cg * 16 + c) * KP + hq * 8;
    const unsigned short* pBl = Bl + (cg * 16 + c) * KP + hq * 8;

    float4 st0, st1, st2, st3, st4;

    #define ISSUE_GATHER(TB)                                                        \
    {                                                                               \
        st0 = *(const float4*)(emb + (size_t)tokens[(TB) + r0] * DIM + j0 * 4);     \
        st1 = *(const float4*)(emb + (size_t)tokens[(TB) + r1] * DIM + j1 * 4);     \
        st2 = *(const float4*)(emb + (size_t)tokens[(TB) + r2] * DIM + j2 * 4);     \
        st3 = *(const float4*)(emb + (size_t)tokens[(TB) + r3] * DIM + j3 * 4);     \
        if (has4) st4 = *(const float4*)(emb + (size_t)tokens[(TB) + r4] * DIM + j4 * 4); \
    }

    // convert one float4 chunk -> 4 bf16 hi + 4 bf16 lo, store to A LDS buffer
    #define STORE_CHUNK(AH, AL, ST, R, J)                                           \
    {                                                                               \
        const unsigned u0 = bc(ST.x) + 0x8000u, u1 = bc(ST.y) + 0x8000u;            \
        const unsigned u2 = bc(ST.z) + 0x8000u, u3 = bc(ST.w) + 0x8000u;            \
        const float q0f = ST.x - asf(u0 & 0xffff0000u);                             \
        const float q1f = ST.y - asf(u1 & 0xffff0000u);                             \
        const float q2f = ST.z - asf(u2 & 0xffff0000u);                             \
        const float q3f = ST.w - asf(u3 & 0xffff0000u);                             \
        *(uint2*)(&(AH)[(R) * LSTR + (J) * 4]) =                                    \
            uint2{perm_hi(u1, u0), perm_hi(u3, u2)};                                \
        *(uint2*)(&(AL)[(R) * LSTR + (J) * 4]) =                                    \
            uint2{perm_hi(bc(q1f) + 0x8000u, bc(q0f) + 0x8000u),                    \
                  perm_hi(bc(q3f) + 0x8000u, bc(q2f) + 0x8000u)};                   \
    }

    #define STAGE_ALL(AH, AL)                                                       \
    {                                                                               \
        STORE_CHUNK(AH, AL, st0, r0, j0); STORE_CHUNK(AH, AL, st1, r1, j1);         \
        STORE_CHUNK(AH, AL, st2, r2, j2); STORE_CHUNK(AH, AL, st3, r3, j3);         \
        if (has4) STORE_CHUNK(AH, AL, st4, r4, j4);                                 \
    }

    // prologue: gather + stage panel 0 into buffer 0
    ISSUE_GATHER(bbase * 32);
    STAGE_ALL(AhL[0], AlL[0]);
    __syncthreads();   // full drain once at start only

    #pragma unroll 1
    for (int p = 0; p < PPB; ++p) {
        const int cur = p & 1, nxt = cur ^ 1;
        // issue next panel's gathers NOW; they ride vmcnt under the whole panel
        if (p + 1 < PPB) ISSUE_GATHER((bbase + p + 1) * 32);
        __builtin_amdgcn_sched_barrier(0);

        // MFMA loop: LDS-A fragments x L2-B fragments + Gram norms
        const unsigned short* pAh = AhL[cur];
        const unsigned short* pAl = AlL[cur];
        f32x4 q0 = {0,0,0,0}, q1 = {0,0,0,0}, q2 = {0,0,0,0};
        f32x4 gv = {0,0,0,0}, g2 = {0,0,0,0};
        #pragma unroll
        for (int t = 0; t < 10; ++t) {
            const s16x8 ah = *(const s16x8*)(pAh + abase + t * 32);
            const s16x8 al = *(const s16x8*)(pAl + abase + t * 32);
            const s16x8 bh = *(const s16x8*)(pBh + t * 32);
            const s16x8 bl = *(const s16x8*)(pBl + t * 32);
            q0 = __builtin_amdgcn_mfma_f32_16x16x32_bf16(ah, bh, q0, 0, 0, 0);
            q1 = __builtin_amdgcn_mfma_f32_16x16x32_bf16(ah, bl, q1, 0, 0, 0);
            q2 = __builtin_amdgcn_mfma_f32_16x16x32_bf16(al, bh, q2, 0, 0, 0);
            gv = __builtin_amdgcn_mfma_f32_16x16x32_bf16(ah, ah, gv, 0, 0, 0);
            g2 = __builtin_amdgcn_mfma_f32_16x16x32_bf16(ah, al, g2, 0, 0, 0);
        }

        // diagonal lanes own |row rb+c|^2 (4 col-group waves race: identical values)
        if (hq == (c >> 2)) {
            const int q = c & 3;
            const float d1 = (q == 0) ? gv[0] : (q == 1) ? gv[1] : (q == 2) ? gv[2] : gv[3];
            const float d2 = (q == 0) ? g2[0] : (q == 1) ? g2[1] : (q == 2) ? g2[2] : g2[3];
            norms[rb + c] = d1 + 2.f * d2;
        }
        asm volatile("s_waitcnt lgkmcnt(0)" ::: "memory");   // intra-wave write->read
        const f32x4 n4 = *(const f32x4*)&norms[rb + hq * 4];
        float4 vv;
        #pragma unroll
        for (int q = 0; q < 4; ++q) {
            const float rn = __builtin_amdgcn_rcpf(
                fmaxf(__builtin_amdgcn_sqrtf(n4[q]), 1e-8f));
            ((float*)&vv)[q] = (q0[q] + q1[q] + q2[q]) * rn;
        }
        // coalesced sm store [b][ch][s][r]
        *(float4*)(smG + ((size_t)((bbase + p) * 2 + chn) * 32 + sb + c) * 32 + rb + hq * 4) = vv;

        if (p + 1 < PPB) {
            // stage into the OTHER buffer; compiler emits counted vmcnt for st regs
            STAGE_ALL(AhL[nxt], AlL[nxt]);
        }
        // raw lgkm-only barrier: ds_writes visible; vmcnt NOT force-drained
        asm volatile("s_waitcnt lgkmcnt(0)" ::: "memory");
        __builtin_amdgcn_s_barrier();
        __builtin_amdgcn_sched_barrier(0);
    }
    #undef STAGE_ALL
    #undef STORE_CHUNK
    #undef ISSUE_GATHER
}

// ---------------- kernel 3: tail per batch (softmax-gate + conv1 + conv2 + fc)
__global__ __launch_bounds__(256) void tail_kernel(
    const float* __restrict__ smG,
    const float* __restrict__ c1w, const float* __restrict__ c1b,
    const float* __restrict__ c2w, const float* __restrict__ c2b,
    const float* __restrict__ f2w, const float* __restrict__ f2b,
    const float* __restrict__ fcw, const float* __restrict__ fcb,
    float* __restrict__ out) {

    __shared__ __attribute__((aligned(16))) float smP[34 * SMST];  // [xp=r+1][ch][yp=s+1]
    __shared__ __attribute__((aligned(16))) float pl1P[2 * 17 * 18];
    __shared__ float scrP[8];    // [0..3]=se_w, [4..7]=sv_w

    const int tid = threadIdx.x;
    const int w = tid >> 6, l = tid & 63;
    const int b = blockIdx.x;

    // P0: zero smP + pl1 borders
    {
        const f32x4 z = {0.f, 0.f, 0.f, 0.f};
        #pragma unroll
        for (int i = 0; i < 3; ++i) {
            const int idx = i * 256 + tid;
            if (idx < 697) ((f32x4*)smP)[idx] = z;
        }
        if (tid >= 190) {
            const int z2 = tid - 190;
            const int ic = (z2 >= 33) ? 1 : 0;
            const int rm = z2 - 33 * ic;
            pl1P[ic * 306 + (rm < 17 ? rm : (rm - 16) * 18)] = 0.f;
        }
    }
    __syncthreads();

    // P1: load sm (coalesced) -> padded LDS + fused softmax partials
    {
        const float* src = smG + (size_t)b * 2048;
        float se = 0.f, sv = 0.f;
        #pragma unroll
        for (int h2 = 0; h2 < 2; ++h2) {
            const int f4 = tid * 2 + h2;            // waves 0-1: ch0; waves 2-3: ch1
            const float4 v = ((const float4*)src)[f4];
            const int base = f4 * 4;
            const int chn = base >> 10;
            const int s = (base >> 5) & 31;
            const int r = base & 31;
            float* dstp = &smP[(r + 1) * SMST + chn * SMY + (s + 1)];
            dstp[0] = v.x; dstp[SMST] = v.y; dstp[2 * SMST] = v.z; dstp[3 * SMST] = v.w;
            const float e0 = __expf(v.x), e1 = __expf(v.y);   // |v|<=1: no max-shift
            const float e2 = __expf(v.z), e3 = __expf(v.w);
            se += e0 + e1 + e2 + e3;
            sv = fmaf(e0, v.x, sv); sv = fmaf(e1, v.y, sv);
            sv = fmaf(e2, v.z, sv); sv = fmaf(e3, v.w, sv);
        }
        #pragma unroll
        for (int m = 32; m >= 1; m >>= 1) { se += __shfl_xor(se, m); sv += __shfl_xor(sv, m); }
        if (l == 0) { scrP[w] = se; scrP[4 + w] = sv; }
    }
    __syncthreads();

    // P2: conv1 (both oc per thread) + gate + relu + maxpool -> pl1P
    {
        const int ii = tid >> 4, jj = tid & 15;
        float pc0[4] = {0,0,0,0}, pc1[4] = {0,0,0,0};
        float pA0[4] = {0,0,0,0}, pA1[4] = {0,0,0,0};
        #pragma unroll
        for (int ic = 0; ic < 2; ++ic) {
            float p[4][4];
            #pragma unroll
            for (int a = 0; a < 4; ++a) {        // xp = 2jj+a, yp base 2ii
                const int off = (2 * jj + a) * SMST + ic * SMY + 2 * ii;
                const float2 v01 = *(const float2*)&smP[off];
                const float2 v23 = *(const float2*)&smP[off + 2];
                p[a][0] = v01.x; p[a][1] = v01.y; p[a][2] = v23.x; p[a][3] = v23.y;
            }
            #pragma unroll
            for (int py = 0; py < 2; ++py)
            #pragma unroll
            for (int px = 0; px < 2; ++px)
            #pragma unroll
            for (int dy = 0; dy < 3; ++dy)
            #pragma unroll
            for (int dx = 0; dx < 3; ++dx) {
                const float pv = p[px + dx][py + dy];
                const int pos = py * 2 + px;
                if (ic == 0) {
                    pc0[pos] = fmaf(c1w[0 * 9 + dy * 3 + dx], pv, pc0[pos]);
                    pc1[pos] = fmaf(c1w[2 * 9 + dy * 3 + dx], pv, pc1[pos]);
                } else {
                    pA0[pos] = fmaf(c1w[1 * 9 + dy * 3 + dx], pv, pA0[pos]);
                    pA1[pos] = fmaf(c1w[3 * 9 + dy * 3 + dx], pv, pA1[pos]);
                }
            }
        }
        const float p0 = (scrP[4] + scrP[5]) / (scrP[0] + scrP[1]);
        const float p1 = (scrP[6] + scrP[7]) / (scrP[2] + scrP[3]);
        const float gg0 = 1.f / (1.f + __expf(-(f2w[0] * p0 + f2w[1] * p1 + f2b[0])));
        const float gg1 = 1.f / (1.f + __expf(-(f2w[2] * p0 + f2w[3] * p1 + f2b[1])));
        const float b0 = c1b[0], b1 = c1b[1];
        float mx0 = 0.f, mx1 = 0.f;   // relu folded
        #pragma unroll
        for (int i = 0; i < 4; ++i) {
            mx0 = fmaxf(mx0, b0 + gg0 * pc0[i] + gg1 * pA0[i]);
            mx1 = fmaxf(mx1, b1 + gg0 * pc1[i] + gg1 * pA1[i]);
        }
        pl1P[0 * 306 + (ii + 1) * 18 + (jj + 1)] = mx0;
        pl1P[1 * 306 + (ii + 1) * 18 + (jj + 1)] = mx1;
    }
    __syncthreads();

    // P3: wave 0: conv2(2x2,pad1)+relu+avgpool2 + fc -> out
    if (w == 0) {
        float o0 = 0.f, o1 = 0.f;
        #pragma unroll
        for (int h = 0; h < 2; ++h) {
            const int o = h * 64 + l, oc2 = o >> 6, ii2 = (o >> 3) & 7, jj2 = o & 7;
            float sum = 0.f;
            #pragma unroll
            for (int py = 0; py < 2; ++py)
            #pragma unroll
            for (int px = 0; px < 2; ++px) {
                const int y = 2 * ii2 + py, x = 2 * jj2 + px;
                float acc = c2b[oc2];
                #pragma unroll
                for (int ic = 0; ic < 2; ++ic)
                #pragma unroll
                for (int dy = 0; dy < 2; ++dy)
                #pragma unroll
                for (int dx = 0; dx < 2; ++dx)
                    acc += c2w[((oc2 * 2 + ic) * 2 + dy) * 2 + dx] *
                           pl1P[ic * 306 + (y + dy) * 18 + (x + dx)];
                sum += fmaxf(acc, 0.f);
            }
            const float val = 0.25f * sum;
            o0 = fmaf(val, fcw[o], o0);
            o1 = fmaf(val, fcw[128 + o], o1);
        }
        #pragma unroll
        for (int m = 32; m >= 1; m >>= 1) { o0 += __shfl_xor(o0, m); o1 += __shfl_xor(o1, m); }
        if (l == 0) {
            out[b * 2 + 0] = fcb[0] + o0;
            out[b * 2 + 1] = fcb[1] + o1;
        }
    }
}

extern "C" void kernel_launch(void* const* d_in, const int* in_sizes, int n_in,
                              void* d_out, int out_size, void* d_ws, size_t ws_size,
                              hipStream_t stream) {
    const int* tokens = (const int*)d_in[0];
    const int* sidx   = (const int*)d_in[1];
    const float* emb  = (const float*)d_in[2];
    const float* c1w  = (const float*)d_in[3];
    const float* c1b  = (const float*)d_in[4];
    const float* c2w  = (const float*)d_in[5];
    const float* c2b  = (const float*)d_in[6];
    const float* f2w  = (const float*)d_in[7];
    const float* f2b  = (const float*)d_in[8];
    const float* fcw  = (const float*)d_in[9];
    const float* fcb  = (const float*)d_in[10];

    // ws layout: [sm f32 4096*2*32*32 = 32 MiB][Bh 40 KiB][Bl 40 KiB]
    float* smG = (float*)d_ws;
    unsigned short* Bh = (unsigned short*)((char*)d_ws + (size_t)NBATCH * 2048 * 4);
    unsigned short* Bl = Bh + NSUP * KP;

    prep_kernel<<<NSUP, 64, 0, stream>>>(sidx, emb, Bh, Bl);
    gemm_kernel<<<GRID_G, 512, 0, stream>>>(tokens, emb, Bh, Bl, smG);
    tail_kernel<<<NBATCH, 256, 0, stream>>>(smG, c1w, c1b, c2w, c2b,
                                            f2w, f2b, fcw, fcb, (float*)d_out);
}